// Round 1
// baseline (178.154 us; speedup 1.0000x reference)
//
#include <hip/hip_runtime.h>

// SynthMorphLoss: soft-dice over int32 label maps + diffusion regularizer.
// B=1, D=160, H=192, W=224, 26 classes (class 0 ignored in dice mean).
// R7: FUSE hist + diff into one dispatch. R6 evidence: both phases run far
// below shared-BW ceilings (aggregate 0.88 TB/s vs 6.3 TB/s HBM) => each is
// per-wave latency/issue bound. They are independent, so co-scheduling their
// waves should overlay the two durations (expect ~max, not sum). Bodies are
// byte-identical to R6 for attribution. Interleave in runs of 8 consecutive
// blocks so the (round-robin) XCD mapping gives every XCD/CU a mix of
// hist waves (LDS-atomic heavy) and diff waves (VMEM heavy).

namespace {
constexpr int NC    = 26;
constexpr int Dd    = 160, Hh = 192, Ww = 224;
constexpr int W4    = Ww / 4;                 // 56 float4 per row
constexpr int PL4   = Hh * W4;                // 10752 float4 per (c,d) plane
constexpr int N4L   = Dd * Hh * Ww / 4;       // 1,720,320 int4 per label map
constexpr int JSTRIDE = 33;                   // joint-hist row stride
constexpr int NBINS   = NC * JSTRIDE;         // 858
constexpr int HIST_BLOCKS = 840;              // 840*256*8 == N4L exact
constexpr int HT          = HIST_BLOCKS * 256;
// diff decomposition: wave owns (c, 6-row h-slab, 5-plane d-chunk)
constexpr int SLAB    = 6;                    // rows per wave
constexpr int SLABS   = Hh / SLAB;            // 32
constexpr int SGRPS   = SLABS / 4;            // 8 slab-groups (4 waves/block)
constexpr int DCH     = 5;                    // d-steps per wave
constexpr int DCHUNKS = Dd / DCH;             // 32
constexpr int DIFF_BLOCKS = 3 * DCHUNKS * SGRPS;   // 768 == 3 * 256 exactly
// fused grid: interleave in groups of 8 blocks (one XCD round).
constexpr int GRP         = 8;
constexpr int DIFF_GRPS   = DIFF_BLOCKS / GRP;     // 96
constexpr int HIST_GRPS   = HIST_BLOCKS / GRP;     // 105
constexpr int PAIRED_GRPS = 2 * DIFF_GRPS;         // 192 (96 diff + 96 hist)
constexpr int FUSED_BLOCKS = DIFF_BLOCKS + HIST_BLOCKS;  // 1608
}

__global__ void init_ws_kernel(unsigned int* __restrict__ joint,
                               double* __restrict__ sums) {
    int i = blockIdx.x * blockDim.x + threadIdx.x;
    if (i < NBINS) joint[i] = 0u;
    if (i < 3)     sums[i]  = 0.0;
}

// ---- hist path (identical to R6 hist_kernel body) ----
__device__ __forceinline__ void hist_path(
        int hb,
        const int4* __restrict__ f4,
        const int4* __restrict__ m4,
        unsigned int* __restrict__ gj) {
    __shared__ unsigned int h[NBINS];
    for (int i = threadIdx.x; i < NBINS; i += 256) h[i] = 0u;
    __syncthreads();

    const int g = hb * 256 + threadIdx.x;
    int4 a0 = f4[g];
    int4 a1 = f4[g + HT];
    int4 a2 = f4[g + 2 * HT];
    int4 a3 = f4[g + 3 * HT];
    int4 a4 = f4[g + 4 * HT];
    int4 a5 = f4[g + 5 * HT];
    int4 a6 = f4[g + 6 * HT];
    int4 a7 = f4[g + 7 * HT];
    int4 b0 = m4[g];
    int4 b1 = m4[g + HT];
    int4 b2 = m4[g + 2 * HT];
    int4 b3 = m4[g + 3 * HT];
    int4 b4 = m4[g + 4 * HT];
    int4 b5 = m4[g + 5 * HT];
    int4 b6 = m4[g + 6 * HT];
    int4 b7 = m4[g + 7 * HT];

#define JACC(A, B)                                   \
    atomicAdd(&h[(A).x * JSTRIDE + (B).x], 1u);      \
    atomicAdd(&h[(A).y * JSTRIDE + (B).y], 1u);      \
    atomicAdd(&h[(A).z * JSTRIDE + (B).z], 1u);      \
    atomicAdd(&h[(A).w * JSTRIDE + (B).w], 1u);
    JACC(a0, b0) JACC(a1, b1) JACC(a2, b2) JACC(a3, b3)
    JACC(a4, b4) JACC(a5, b5) JACC(a6, b6) JACC(a7, b7)
#undef JACC

    __syncthreads();
    for (int i = threadIdx.x; i < NBINS; i += 256) {
        unsigned int v = h[i];
        if (v) atomicAdd(&gj[i], v);
    }
}

// ---- diff path (identical to R6 diff_kernel body, z-carry) ----
__device__ __forceinline__ void diff_path(
        int db,
        const float4* __restrict__ v4,
        double* __restrict__ gs) {
    const int lane = threadIdx.x & 63;
    const int wid  = threadIdx.x >> 6;
    const int c      = db / (DCHUNKS * SGRPS);    // db / 256
    const int rem    = db % (DCHUNKS * SGRPS);
    const int dchunk = rem / SGRPS;
    const int sgrp   = rem % SGRPS;
    const int slab   = sgrp * 4 + wid;
    const int h0     = slab * SLAB;
    const int d0     = dchunk * DCH;
    const bool al    = (lane < W4);
    const bool hv    = (h0 + SLAB < Hh);          // dy-halo row exists
    const int  l     = al ? lane : (W4 - 1);      // clamp inactive lanes

    size_t cur = ((size_t)(c * Dd + d0) * Hh + h0) * W4 + l;

    float4 p0 = v4[cur];
    float4 p1 = v4[cur + W4];
    float4 p2 = v4[cur + 2 * W4];
    float4 p3 = v4[cur + 3 * W4];
    float4 p4 = v4[cur + 4 * W4];
    float4 p5 = v4[cur + 5 * W4];

    float sx = 0.f, sy = 0.f, sz = 0.f;
    const int haloOff = (hv ? SLAB : SLAB - 1) * W4;   // clamp: masked anyway

    for (int k = 0; k < DCH; ++k) {
        const int d = d0 + k;
        const bool dzv = (d < Dd - 1);            // wave-uniform
        float4 hl = v4[cur + haloOff];
        float4 n0 = p0, n1 = p1, n2 = p2, n3 = p3, n4 = p4, n5 = p5;
        if (dzv) {
            const size_t nb = cur + PL4;
            n0 = v4[nb];
            n1 = v4[nb + W4];
            n2 = v4[nb + 2 * W4];
            n3 = v4[nb + 3 * W4];
            n4 = v4[nb + 4 * W4];
            n5 = v4[nb + 5 * W4];
        }

        // dx: 3 interior diffs + crossing diff (lane mask)
#define DX(P)                                                                  \
        {                                                                      \
            float d1 = (P).y - (P).x, d2 = (P).z - (P).y, d3 = (P).w - (P).z;  \
            sx += d1 * d1 + d2 * d2 + d3 * d3;                                 \
            float nx = __shfl_down((P).x, 1);                                  \
            float d4 = nx - (P).w;                                             \
            sx += (lane < W4 - 1) ? d4 * d4 : 0.f;                             \
        }
        DX(p0) DX(p1) DX(p2) DX(p3) DX(p4) DX(p5)
#undef DX
        // dy: rows 0..4 within slab; row 5 against halo (wave-uniform hv)
#define DY(A, B)                                                               \
        {                                                                      \
            float e0 = (B).x - (A).x, e1 = (B).y - (A).y;                      \
            float e2 = (B).z - (A).z, e3 = (B).w - (A).w;                      \
            sy += e0 * e0 + e1 * e1 + e2 * e2 + e3 * e3;                       \
        }
        DY(p0, p1) DY(p1, p2) DY(p2, p3) DY(p3, p4) DY(p4, p5)
        if (hv) DY(p5, hl)
#undef DY
        // dz: next plane minus current (registers), wave-uniform dzv
        if (dzv) {
#define DZ(A, B)                                                               \
            {                                                                  \
                float e0 = (B).x - (A).x, e1 = (B).y - (A).y;                  \
                float e2 = (B).z - (A).z, e3 = (B).w - (A).w;                  \
                sz += e0 * e0 + e1 * e1 + e2 * e2 + e3 * e3;                   \
            }
            DZ(p0, n0) DZ(p1, n1) DZ(p2, n2) DZ(p3, n3) DZ(p4, n4) DZ(p5, n5)
#undef DZ
        }
        p0 = n0; p1 = n1; p2 = n2; p3 = n3; p4 = n4; p5 = n5;
        cur += PL4;
    }

    if (!al) { sx = 0.f; sy = 0.f; sz = 0.f; }    // clamped lanes: drop dupes

    #pragma unroll
    for (int off = 32; off > 0; off >>= 1) {
        sx += __shfl_down(sx, off);
        sy += __shfl_down(sy, off);
        sz += __shfl_down(sz, off);
    }
    __shared__ float px[4], py[4], pz[4];
    if (lane == 0) { px[wid] = sx; py[wid] = sy; pz[wid] = sz; }
    __syncthreads();
    if (threadIdx.x == 0) {
        atomicAdd(&gs[0], (double)(px[0] + px[1] + px[2] + px[3]));
        atomicAdd(&gs[1], (double)(py[0] + py[1] + py[2] + py[3]));
        atomicAdd(&gs[2], (double)(pz[0] + pz[1] + pz[2] + pz[3]));
    }
}

// Fused dispatch: groups of 8 consecutive blocks alternate diff/hist so the
// XCD round-robin mapping gives every XCD both wave types concurrently.
// Launch bounds take diff's (the VGPR-heavier path): 3 blocks/CU.
__global__ __launch_bounds__(256, 3) void fused_kernel(
        const int4* __restrict__ f4,
        const int4* __restrict__ m4,
        unsigned int* __restrict__ gj,
        const float4* __restrict__ v4,
        double* __restrict__ gs) {
    const int grp = blockIdx.x >> 3;          // group of 8 blocks
    const int t   = blockIdx.x & 7;
    if (grp < PAIRED_GRPS) {
        const int idx = (grp >> 1) * GRP + t; // 0..767 within each type
        if (grp & 1) hist_path(idx, f4, m4, gj);
        else         diff_path(idx, v4, gs);
    } else {
        // hist tail: 768..839
        hist_path(DIFF_BLOCKS + (grp - PAIRED_GRPS) * GRP + t, f4, m4, gj);
    }
}

__global__ void finalize_kernel(const unsigned int* __restrict__ gj,
                                const double* __restrict__ gs,
                                float* __restrict__ out) {
    int lane = threadIdx.x & 63;
    float term = 0.f;
    if (lane >= 1 && lane < NC) {
        float fv = 0.f, mv = 0.f;
        #pragma unroll
        for (int m = 0; m < NC; ++m) fv += (float)gj[lane * JSTRIDE + m];
        #pragma unroll
        for (int f = 0; f < NC; ++f) mv += (float)gj[f * JSTRIDE + lane];
        float iv = (float)gj[lane * JSTRIDE + lane];
        term = (2.f * iv + 1e-5f) / (fv + mv + 1e-5f);
    }
    #pragma unroll
    for (int off = 32; off > 0; off >>= 1) term += __shfl_down(term, off);
    if (threadIdx.x == 0 && blockIdx.x == 0) {
        float sim = 1.f - term * (1.f / 25.f);
        double mdx = gs[0] / ((double)3 * Dd * Hh * (Ww - 1));
        double mdy = gs[1] / ((double)3 * Dd * (Hh - 1) * Ww);
        double mdz = gs[2] / ((double)3 * (Dd - 1) * Hh * Ww);
        float smooth = (float)((mdx + mdy + mdz) / 3.0);
        out[0] = sim + smooth;
        out[1] = sim;
        out[2] = smooth;
    }
}

extern "C" void kernel_launch(void* const* d_in, const int* in_sizes, int n_in,
                              void* d_out, int out_size, void* d_ws, size_t ws_size,
                              hipStream_t stream) {
    const int*   fl = (const int*)d_in[0];
    const int*   ml = (const int*)d_in[1];
    const float* vf = (const float*)d_in[2];
    float* out = (float*)d_out;

    // workspace: [0, 3432) joint counts (858 uints); [3584, 3608) double sums[3]
    unsigned int* joint = (unsigned int*)d_ws;
    double*       sums  = (double*)((char*)d_ws + 3584);

    init_ws_kernel<<<1, 1024, 0, stream>>>(joint, sums);
    fused_kernel<<<FUSED_BLOCKS, 256, 0, stream>>>(
        (const int4*)fl, (const int4*)ml, joint, (const float4*)vf, sums);
    finalize_kernel<<<1, 64, 0, stream>>>(joint, sums, out);
}